// Round 1
// baseline (211.946 us; speedup 1.0000x reference)
//
#include <hip/hip_runtime.h>
#include <hip/hip_bf16.h>

// Problem constants (fixed by the reference).
#define N_NODES 10000
#define DEG     32
#define CH      16
#define IN_DIM  4
#define BATCH   8
#define E_EDGES (N_NODES * DEG)   // 320000
#define EMOD    (E_EDGES / CH)    // 20000 : (16e+c) mod E == 16*(e mod 20000)+c

// Kernel 1: transpose/pad x[B][N][4] -> xt[N+1][B][4] (node-major, 128 B per node).
// Row N_NODES is the zero pad (edges may index node == N_NODES).
__global__ void lcg_transpose(const float* __restrict__ x, float* __restrict__ xt) {
    int tid = blockIdx.x * 256 + threadIdx.x;
    if (tid >= (N_NODES + 1) * BATCH * IN_DIM) return;
    int node = tid >> 5;      // /32
    int r    = tid & 31;
    int b    = r >> 2;        // /4
    int i    = r & 3;
    float v = 0.0f;
    if (node < N_NODES) v = x[(b * N_NODES + node) * IN_DIM + i];
    xt[tid] = v;
}

// Kernel 2: one thread per (n, c). acc over 8 batches in registers.
// out[b,n,c] = sum_i sum_d xt[edges[(16*(n*32+d)+c) mod E]][b][i] * w[i][n*32+d][c]
__global__ __launch_bounds__(128) void lcg_main(
    const float* __restrict__ xt,     // [N+1][8][4]
    const int*   __restrict__ edges,  // [E] (int32 per harness)
    const float* __restrict__ w,      // [4][E][16]
    float*       __restrict__ out)    // [8][N][16]
{
    int tid = blockIdx.x * 128 + threadIdx.x;   // grid covers exactly N*CH
    int n = tid >> 4;
    int c = tid & 15;

    float acc[BATCH];
#pragma unroll
    for (int b = 0; b < BATCH; b++) acc[b] = 0.0f;

    // e = n*32 + d ; edge index k = 16*e + c (mod E) = 16*((n*32+d) mod 20000) + c
    int m = (n * DEG) % EMOD;                 // < 20000, computed once
    const float* wp = w + n * (DEG * CH) + c; // w[0][n*32][c]

#pragma unroll 4
    for (int d = 0; d < DEG; d++) {
        int e1 = m + d;
        if (e1 >= EMOD) e1 -= EMOD;
        int node = edges[e1 * CH + c];

        const float4* xv = (const float4*)(xt + node * (BATCH * IN_DIM));
        float w0 = wp[d * CH + 0 * E_EDGES * CH];
        float w1 = wp[d * CH + 1 * E_EDGES * CH];
        float w2 = wp[d * CH + 2 * E_EDGES * CH];
        float w3 = wp[d * CH + 3 * E_EDGES * CH];

#pragma unroll
        for (int b = 0; b < BATCH; b++) {
            float4 xb = xv[b];
            acc[b] += xb.x * w0 + xb.y * w1 + xb.z * w2 + xb.w * w3;
        }
    }

#pragma unroll
    for (int b = 0; b < BATCH; b++) {
        out[b * (N_NODES * CH) + tid] = acc[b];  // b*160000 + n*16 + c
    }
}

extern "C" void kernel_launch(void* const* d_in, const int* in_sizes, int n_in,
                              void* d_out, int out_size, void* d_ws, size_t ws_size,
                              hipStream_t stream) {
    const float* x     = (const float*)d_in[0];   // [8][10000][4] f32
    const int*   edges = (const int*)d_in[1];     // [320000] int
    const float* w     = (const float*)d_in[2];   // [4][320000][16] f32
    float* out = (float*)d_out;                   // [8][10000][16] f32
    float* xt  = (float*)d_ws;                    // (10001*32) f32 = 1.28 MB

    int tr_total  = (N_NODES + 1) * BATCH * IN_DIM;       // 320032
    int tr_blocks = (tr_total + 255) / 256;               // 1251
    lcg_transpose<<<tr_blocks, 256, 0, stream>>>(x, xt);

    int main_threads = N_NODES * CH;                      // 160000
    lcg_main<<<main_threads / 128, 128, 0, stream>>>(xt, edges, w, out);
}

// Round 2
// 133.359 us; speedup vs baseline: 1.5893x; 1.5893x over previous
//
#include <hip/hip_runtime.h>
#include <hip/hip_bf16.h>

// Problem constants (fixed by the reference).
#define N_NODES 10000
#define DEG     32
#define CH      16
#define IN_DIM  4
#define BATCH   8
#define E_EDGES (N_NODES * DEG)        // 320000
#define WI_STRIDE (E_EDGES * CH)       // 5,120,000 floats between w[i] planes
#define P_COUNT 625                    // 512*625 == E_EDGES : gather period in n

// Kernel 1: transpose/pad x[B][N][4] -> xt[N+1][B][4] (node-major, 128 B/node).
// Reads are perfectly coalesced float4 (x is [b][node][4]); writes scatter in
// 16 B chunks with node-consecutive lanes (stride 128 B) - L2 write combine.
__global__ __launch_bounds__(256) void lcg_transpose(const float* __restrict__ x,
                                                     float* __restrict__ xt) {
    int t = blockIdx.x * 256 + threadIdx.x;
    if (t < BATCH * N_NODES) {
        int b = t / N_NODES;
        int node = t - b * N_NODES;
        float4 v = *(const float4*)(x + 4 * t);          // x[b][node][0..3]
        *(float4*)(xt + node * 32 + b * 4) = v;
    } else if (t < BATCH * N_NODES + 8) {
        int r = t - BATCH * N_NODES;                     // zero pad row N_NODES
        *(float4*)(xt + N_NODES * 32 + r * 4) = make_float4(0.f, 0.f, 0.f, 0.f);
    }
}

// Kernel 2: block = (p, c-half). Exploits 16x gather reuse:
//   gather index k = (512 n + 16 d + c) mod 320000, and n = p + 625 j all share
//   k = 512 p + 16 d + c. Edge slots per p are edges[512p .. 512p+512).
// Stage A: gather 256 node-rows (32 floats each) into LDS (stride 36 words:
//   bank shift 4/slot -> <=2-way conflicts, 16B-aligned for b128).
// Stage B: thread (j, c_l, bhalf) accumulates 4 batches over d, streaming
//   single-use weights coalesced from HBM and x-rows from LDS.
__global__ __launch_bounds__(256, 4) void lcg_main(
    const float* __restrict__ xt,     // [N+1][32]
    const int*   __restrict__ edges,  // [E]
    const float* __restrict__ w,      // [4][E][16]
    float*       __restrict__ out)    // [8][N][16]
{
    __shared__ float lx[256 * 36];    // 36864 B -> 4 blocks/CU

    int bid = blockIdx.x;
    int p  = bid >> 1;                // 0..624
    int ch = bid & 1;                 // c-half
    int t  = threadIdx.x;

    // ---- Stage A: edges + gather into LDS ----
    {
        int sub  = t & 7;             // which float4 of the 128 B node row
        int sidx = t >> 3;            // 0..31 ; slots s = sidx + 32k
        int nd[8];
#pragma unroll
        for (int k = 0; k < 8; k++) {
            int s = sidx + 32 * k;            // s = d*8 + c_l
            int d = s >> 3, c_l = s & 7;
            nd[k] = edges[512 * p + 16 * d + 8 * ch + c_l];
        }
#pragma unroll
        for (int k = 0; k < 8; k++) {
            int s = sidx + 32 * k;
            float4 v = *(const float4*)(xt + nd[k] * 32 + sub * 4);
            *(float4*)(&lx[s * 36 + sub * 4]) = v;
        }
    }
    __syncthreads();

    // ---- Stage B: compute ----
    int c_l = t & 7;
    int bh  = (t >> 3) & 1;
    int j   = t >> 4;                 // 0..15
    int n   = p + P_COUNT * j;
    int c   = ch * 8 + c_l;

    const float* wp = w + (n * DEG) * CH + c;   // w[0][32n][c]
    float acc0 = 0.f, acc1 = 0.f, acc2 = 0.f, acc3 = 0.f;

#pragma unroll 4
    for (int d = 0; d < DEG; d++) {
        float w0 = wp[d * CH];
        float w1 = wp[d * CH + WI_STRIDE];
        float w2 = wp[d * CH + 2 * WI_STRIDE];
        float w3 = wp[d * CH + 3 * WI_STRIDE];
        const float* lp = &lx[(d * 8 + c_l) * 36 + 16 * bh];
        float4 x0 = *(const float4*)(lp);
        float4 x1 = *(const float4*)(lp + 4);
        float4 x2 = *(const float4*)(lp + 8);
        float4 x3 = *(const float4*)(lp + 12);
        acc0 += x0.x * w0 + x0.y * w1 + x0.z * w2 + x0.w * w3;
        acc1 += x1.x * w0 + x1.y * w1 + x1.z * w2 + x1.w * w3;
        acc2 += x2.x * w0 + x2.y * w1 + x2.z * w2 + x2.w * w3;
        acc3 += x3.x * w0 + x3.y * w1 + x3.z * w2 + x3.w * w3;
    }

    int ob = n * CH + c;
    out[(4 * bh + 0) * (N_NODES * CH) + ob] = acc0;
    out[(4 * bh + 1) * (N_NODES * CH) + ob] = acc1;
    out[(4 * bh + 2) * (N_NODES * CH) + ob] = acc2;
    out[(4 * bh + 3) * (N_NODES * CH) + ob] = acc3;
}

extern "C" void kernel_launch(void* const* d_in, const int* in_sizes, int n_in,
                              void* d_out, int out_size, void* d_ws, size_t ws_size,
                              hipStream_t stream) {
    const float* x     = (const float*)d_in[0];   // [8][10000][4] f32
    const int*   edges = (const int*)d_in[1];     // [320000] int
    const float* w     = (const float*)d_in[2];   // [4][320000][16] f32
    float* out = (float*)d_out;                   // [8][10000][16] f32
    float* xt  = (float*)d_ws;                    // (10001*32) f32 = 1.28 MB

    int tr_total  = BATCH * N_NODES + 8;                  // 80008
    int tr_blocks = (tr_total + 255) / 256;               // 313
    lcg_transpose<<<tr_blocks, 256, 0, stream>>>(x, xt);

    lcg_main<<<2 * P_COUNT, 256, 0, stream>>>(xt, edges, w, out);
}